// Round 4
// baseline (660.183 us; speedup 1.0000x reference)
//
#include <hip/hip_runtime.h>

// GCN: 3x GCNConv(64->64) + mean-pool(32 graphs) + linear(64->2), fp32.
// Strategy: build CSR-by-dst once (norm coefficients are layer-invariant),
// then each layer = dense 64x64 GEMM + per-node register-accumulated gather
// (no float atomics).
//
// Defensive: if ws_size is smaller than the ~33 MB we need, launch nothing
// (clean absmax failure instead of OOB writes crashing the container).

#define FEAT 64
#define NGRAPH 32
#define SCAN_BLK 512

// ---------------- preprocessing ----------------

__global__ void k_init(float* __restrict__ deg, int* __restrict__ cnt,
                       int* __restrict__ cursor, int n) {
    int i = blockIdx.x * blockDim.x + threadIdx.x;
    int stride = gridDim.x * blockDim.x;
    for (; i < n; i += stride) { deg[i] = 1.0f; cnt[i] = 0; cursor[i] = 0; }
}

__global__ void k_deg(const int* __restrict__ dst, const float* __restrict__ ew,
                      float* __restrict__ deg, int* __restrict__ cnt, int e) {
    int i = blockIdx.x * blockDim.x + threadIdx.x;
    int stride = gridDim.x * blockDim.x;
    for (; i < e; i += stride) {
        int d = dst[i];
        atomicAdd(&deg[d], ew[i]);
        atomicAdd(&cnt[d], 1);
    }
}

__global__ void k_dis(const float* __restrict__ deg, float* __restrict__ dis, int n) {
    int i = blockIdx.x * blockDim.x + threadIdx.x;
    if (i < n) dis[i] = rsqrtf(deg[i]);   // deg >= 1 always (self loop)
}

// per-block inclusive scan -> writes local-exclusive into row_ptr, block sums into part
__global__ void k_scan_block(const int* __restrict__ cnt, int n,
                             int* __restrict__ row_ptr, int* __restrict__ part) {
    __shared__ int s[SCAN_BLK];
    int tid = threadIdx.x;
    int i = blockIdx.x * SCAN_BLK + tid;
    int v = (i < n) ? cnt[i] : 0;
    s[tid] = v;
    __syncthreads();
    for (int o = 1; o < SCAN_BLK; o <<= 1) {
        int t = (tid >= o) ? s[tid - o] : 0;
        __syncthreads();
        s[tid] += t;
        __syncthreads();
    }
    if (i < n) row_ptr[i] = s[tid] - v;          // local exclusive
    if (tid == SCAN_BLK - 1) part[blockIdx.x] = s[tid];
}

__global__ void k_scan_top(int* __restrict__ part, int nb) {
    __shared__ int s[SCAN_BLK];
    int tid = threadIdx.x;
    int v = (tid < nb) ? part[tid] : 0;
    s[tid] = v;
    __syncthreads();
    for (int o = 1; o < SCAN_BLK; o <<= 1) {
        int t = (tid >= o) ? s[tid - o] : 0;
        __syncthreads();
        s[tid] += t;
        __syncthreads();
    }
    if (tid < nb) part[tid] = s[tid] - v;        // exclusive block offsets
}

__global__ void k_scan_add(int* __restrict__ row_ptr, const int* __restrict__ part,
                           int n, int e) {
    int i = blockIdx.x * blockDim.x + threadIdx.x;
    if (i < n) row_ptr[i] += part[i >> 9];       // 512 = 2^9
    if (i == 0) row_ptr[n] = e;
}

__global__ void k_fill(const int* __restrict__ src, const int* __restrict__ dst,
                       const float* __restrict__ ew, const float* __restrict__ dis,
                       const int* __restrict__ row_ptr, int* __restrict__ cursor,
                       int* __restrict__ csr_src, float* __restrict__ csr_norm, int e) {
    int i = blockIdx.x * blockDim.x + threadIdx.x;
    int stride = gridDim.x * blockDim.x;
    for (; i < e; i += stride) {
        int d = dst[i];
        int s = src[i];
        int pos = row_ptr[d] + atomicAdd(&cursor[d], 1);
        csr_src[pos] = s;
        csr_norm[pos] = dis[s] * ew[i] * dis[d];
    }
}

// ---------------- per-layer kernels ----------------

// H[n][64] = X[n][64] @ W[64][64]; W staged in LDS; 64 rows per block.
__global__ void k_gemm(const float* __restrict__ X, const float* __restrict__ W,
                       float* __restrict__ H, int n) {
    __shared__ float w[FEAT * FEAT];
    for (int t = threadIdx.x; t < FEAT * FEAT; t += blockDim.x) w[t] = W[t];
    __syncthreads();
    int j = threadIdx.x & 63;
    int sub = threadIdx.x >> 6;
    int base = blockIdx.x * 64;
    for (int r = sub; r < 64; r += 4) {
        int i = base + r;
        if (i >= n) break;
        const float* xr = X + (size_t)i * FEAT;
        float acc = 0.f;
        #pragma unroll
        for (int k = 0; k < FEAT; ++k) acc = fmaf(xr[k], w[k * FEAT + j], acc);
        H[(size_t)i * FEAT + j] = acc;
    }
}

// out[i][f] = b[f] + dis[i]^2 * H[i][f] + sum_{e in CSR row i} norm[e]*H[src[e]][f]
__global__ void k_conv(const float* __restrict__ H, const int* __restrict__ row_ptr,
                       const int* __restrict__ csr_src, const float* __restrict__ csr_norm,
                       const float* __restrict__ dis, const float* __restrict__ bias,
                       float* __restrict__ OUT, int n, int do_relu) {
    int g = blockIdx.x * blockDim.x + threadIdx.x;
    int node = g >> 6;
    int f = g & 63;
    if (node >= n) return;
    int beg = row_ptr[node];
    int end = row_ptr[node + 1];
    float acc = 0.f;
    for (int j = beg; j < end; ++j) {
        int s = csr_src[j];          // wave-uniform broadcast
        float nm = csr_norm[j];      // wave-uniform broadcast
        acc = fmaf(nm, H[(size_t)s * FEAT + f], acc);   // coalesced 256B/wave
    }
    float di = dis[node];
    acc = fmaf(di * di, H[(size_t)node * FEAT + f], acc);
    acc += bias[f];
    if (do_relu) acc = fmaxf(acc, 0.f);
    OUT[(size_t)node * FEAT + f] = acc;
}

// ---------------- pooling + head ----------------

__device__ __forceinline__ int lb(const int* __restrict__ a, int n, int v) {
    int lo = 0, hi = n;
    while (lo < hi) { int m = (lo + hi) >> 1; if (a[m] < v) lo = m + 1; else hi = m; }
    return lo;
}

__global__ void k_pool(const float* __restrict__ H, const int* __restrict__ batch,
                       float* __restrict__ pooled, int n) {
    __shared__ float red[256];
    int g = blockIdx.x;                       // graph id
    int start = lb(batch, n, g);
    int end = lb(batch, n, g + 1);
    int f = threadIdx.x & 63;
    int sub = threadIdx.x >> 6;
    float acc = 0.f;
    for (int i = start + sub; i < end; i += 4) acc += H[(size_t)i * FEAT + f];
    red[threadIdx.x] = acc;
    __syncthreads();
    if (sub == 0) {
        float s = red[f] + red[64 + f] + red[128 + f] + red[192 + f];
        float c = fmaxf((float)(end - start), 1.0f);
        pooled[g * FEAT + f] = s / c;
    }
}

__global__ void k_head(const float* __restrict__ pooled, const float* __restrict__ Wl,
                       const float* __restrict__ bl, float* __restrict__ out, int C) {
    int t = threadIdx.x;
    if (t >= NGRAPH * C) return;
    int g = t / C, c = t % C;
    float acc = bl[c];
    #pragma unroll
    for (int f = 0; f < FEAT; ++f) acc = fmaf(pooled[g * FEAT + f], Wl[f * C + c], acc);
    out[g * C + c] = acc;
}

// ---------------- launch ----------------

extern "C" void kernel_launch(void* const* d_in, const int* in_sizes, int n_in,
                              void* d_out, int out_size, void* d_ws, size_t ws_size,
                              hipStream_t stream) {
    const float* x     = (const float*)d_in[0];
    const int*   ei    = (const int*)d_in[1];
    const float* ew    = (const float*)d_in[2];
    const int*   batch = (const int*)d_in[3];
    const float* W1 = (const float*)d_in[4];
    const float* b1 = (const float*)d_in[5];
    const float* W2 = (const float*)d_in[6];
    const float* b2 = (const float*)d_in[7];
    const float* W3 = (const float*)d_in[8];
    const float* b3 = (const float*)d_in[9];
    const float* Wl = (const float*)d_in[10];
    const float* bl = (const float*)d_in[11];
    float* out = (float*)d_out;

    const int N = in_sizes[3];          // batch has N elements
    const int E = in_sizes[2];          // edge_attr has E elements
    const int C = in_sizes[11];         // bl has C elements

    const int* src = ei;
    const int* dst = ei + E;

    // workspace carve-up (all 256B-aligned); dry-run first to check ws_size
    size_t need = 0;
    auto sz = [&](size_t bytes) { need += (bytes + 255) & ~(size_t)255; };
    sz((size_t)N * 4); sz((size_t)N * 4); sz((size_t)N * 4);
    sz((size_t)(N + 1) * 4); sz((size_t)N * 4); sz((size_t)SCAN_BLK * 4);
    sz((size_t)E * 4); sz((size_t)E * 4);
    sz((size_t)N * FEAT * 4); sz((size_t)N * FEAT * 4);
    sz((size_t)NGRAPH * FEAT * 4);
    if (need > ws_size) return;   // fail readable (zero output), not fatal

    char* p = (char*)d_ws;
    auto carve = [&](size_t bytes) {
        char* r = p;
        p += (bytes + 255) & ~(size_t)255;
        return r;
    };
    float* deg      = (float*)carve((size_t)N * 4);
    float* dis      = (float*)carve((size_t)N * 4);
    int*   cnt      = (int*)  carve((size_t)N * 4);
    int*   row_ptr  = (int*)  carve((size_t)(N + 1) * 4);
    int*   cursor   = (int*)  carve((size_t)N * 4);
    int*   part     = (int*)  carve((size_t)SCAN_BLK * 4);
    int*   csr_src  = (int*)  carve((size_t)E * 4);
    float* csr_norm = (float*)carve((size_t)E * 4);
    float* bufA     = (float*)carve((size_t)N * FEAT * 4);
    float* bufB     = (float*)carve((size_t)N * FEAT * 4);
    float* pooled   = (float*)carve((size_t)NGRAPH * FEAT * 4);

    const int blkN  = (N + 255) / 256;
    const int blkE  = (E + 255) / 256;
    const int nScan = (N + SCAN_BLK - 1) / SCAN_BLK;
    const int blkNF = (N * FEAT + 255) / 256;
    const int blkG  = (N + 63) / 64;

    // structure preprocessing (layer-invariant)
    k_init<<<blkN, 256, 0, stream>>>(deg, cnt, cursor, N);
    k_deg<<<blkE, 256, 0, stream>>>(dst, ew, deg, cnt, E);
    k_dis<<<blkN, 256, 0, stream>>>(deg, dis, N);
    k_scan_block<<<nScan, SCAN_BLK, 0, stream>>>(cnt, N, row_ptr, part);
    k_scan_top<<<1, SCAN_BLK, 0, stream>>>(part, nScan);
    k_scan_add<<<blkN, 256, 0, stream>>>(row_ptr, part, N, E);
    k_fill<<<blkE, 256, 0, stream>>>(src, dst, ew, dis, row_ptr, cursor,
                                     csr_src, csr_norm, E);

    // layer 1
    k_gemm<<<blkG, 256, 0, stream>>>(x, W1, bufA, N);
    k_conv<<<blkNF, 256, 0, stream>>>(bufA, row_ptr, csr_src, csr_norm, dis, b1,
                                      bufB, N, 1);
    // layer 2
    k_gemm<<<blkG, 256, 0, stream>>>(bufB, W2, bufA, N);
    k_conv<<<blkNF, 256, 0, stream>>>(bufA, row_ptr, csr_src, csr_norm, dis, b2,
                                      bufB, N, 1);
    // layer 3
    k_gemm<<<blkG, 256, 0, stream>>>(bufB, W3, bufA, N);
    k_conv<<<blkNF, 256, 0, stream>>>(bufA, row_ptr, csr_src, csr_norm, dis, b3,
                                      bufB, N, 0);

    // pool + head
    k_pool<<<NGRAPH, 256, 0, stream>>>(bufB, batch, pooled, N);
    k_head<<<1, 64, 0, stream>>>(pooled, Wl, bl, out, C);
}

// Round 8
// 468.227 us; speedup vs baseline: 1.4100x; 1.4100x over previous
//
#include <hip/hip_runtime.h>

// GCN: 3x GCNConv(64->64) + mean-pool(32 graphs) + linear(64->2), fp32.
// CSR-by-dst built once; each layer = dense 64x64 GEMM + per-node gather.
// Pool = segmented per-wave reduction over sorted batch ids (atomic flush
// only at graph boundaries); mean + head fused into k_head.

#define FEAT 64
#define NGRAPH 32
#define SCAN_BLK 512
#define POOL_SPAN 64

// ---------------- preprocessing ----------------

__global__ void k_init(float* __restrict__ deg, int* __restrict__ cnt,
                       int* __restrict__ cursor, float* __restrict__ sums, int n) {
    int i = blockIdx.x * blockDim.x + threadIdx.x;
    int stride = gridDim.x * blockDim.x;
    for (; i < n; i += stride) {
        deg[i] = 1.0f; cnt[i] = 0; cursor[i] = 0;
        if (i < NGRAPH * FEAT) sums[i] = 0.0f;
    }
}

__global__ void k_deg(const int* __restrict__ dst, const float* __restrict__ ew,
                      float* __restrict__ deg, int* __restrict__ cnt, int e) {
    int i = blockIdx.x * blockDim.x + threadIdx.x;
    int stride = gridDim.x * blockDim.x;
    for (; i < e; i += stride) {
        int d = dst[i];
        atomicAdd(&deg[d], ew[i]);
        atomicAdd(&cnt[d], 1);
    }
}

// per-block inclusive scan of cnt -> local-exclusive row_ptr + block sums;
// also computes dis = rsqrt(deg) (deg >= 1 from self-loop).
__global__ void k_scan_block(const int* __restrict__ cnt, int n,
                             int* __restrict__ row_ptr, int* __restrict__ part,
                             const float* __restrict__ deg, float* __restrict__ dis) {
    __shared__ int s[SCAN_BLK];
    int tid = threadIdx.x;
    int i = blockIdx.x * SCAN_BLK + tid;
    int v = (i < n) ? cnt[i] : 0;
    if (i < n) dis[i] = rsqrtf(deg[i]);
    s[tid] = v;
    __syncthreads();
    for (int o = 1; o < SCAN_BLK; o <<= 1) {
        int t = (tid >= o) ? s[tid - o] : 0;
        __syncthreads();
        s[tid] += t;
        __syncthreads();
    }
    if (i < n) row_ptr[i] = s[tid] - v;          // local exclusive
    if (tid == SCAN_BLK - 1) part[blockIdx.x] = s[tid];
}

__global__ void k_scan_top(int* __restrict__ part, int nb) {
    __shared__ int s[SCAN_BLK];
    int tid = threadIdx.x;
    int v = (tid < nb) ? part[tid] : 0;
    s[tid] = v;
    __syncthreads();
    for (int o = 1; o < SCAN_BLK; o <<= 1) {
        int t = (tid >= o) ? s[tid - o] : 0;
        __syncthreads();
        s[tid] += t;
        __syncthreads();
    }
    if (tid < nb) part[tid] = s[tid] - v;        // exclusive block offsets
}

__global__ void k_scan_add(int* __restrict__ row_ptr, const int* __restrict__ part,
                           int n, int e) {
    int i = blockIdx.x * blockDim.x + threadIdx.x;
    if (i < n) row_ptr[i] += part[i >> 9];       // 512 = 2^9
    if (i == 0) row_ptr[n] = e;
}

// CSR entry packed as int2{src, norm-bits}: one 8B load per edge in conv.
__global__ void k_fill(const int* __restrict__ src, const int* __restrict__ dst,
                       const float* __restrict__ ew, const float* __restrict__ dis,
                       const int* __restrict__ row_ptr, int* __restrict__ cursor,
                       int2* __restrict__ csr, int e) {
    int i = blockIdx.x * blockDim.x + threadIdx.x;
    int stride = gridDim.x * blockDim.x;
    for (; i < e; i += stride) {
        int d = dst[i];
        int s = src[i];
        int pos = row_ptr[d] + atomicAdd(&cursor[d], 1);
        float nm = dis[s] * ew[i] * dis[d];
        csr[pos] = make_int2(s, __float_as_int(nm));
    }
}

// ---------------- per-layer kernels ----------------

// H[n][64] = X[n][64] @ W[64][64]; W staged in LDS; 64 rows per block.
__global__ void k_gemm(const float* __restrict__ X, const float* __restrict__ W,
                       float* __restrict__ H, int n) {
    __shared__ float w[FEAT * FEAT];
    for (int t = threadIdx.x; t < FEAT * FEAT; t += blockDim.x) w[t] = W[t];
    __syncthreads();
    int j = threadIdx.x & 63;
    int sub = threadIdx.x >> 6;
    int base = blockIdx.x * 64;
    for (int r = sub; r < 64; r += 4) {
        int i = base + r;
        if (i >= n) break;
        const float* xr = X + (size_t)i * FEAT;
        float acc = 0.f;
        #pragma unroll
        for (int k = 0; k < FEAT; ++k) acc = fmaf(xr[k], w[k * FEAT + j], acc);
        H[(size_t)i * FEAT + j] = acc;
    }
}

// out[i][f] = b[f] + dis[i]^2 * H[i][f] + sum_{e in CSR row i} norm[e]*H[src[e]][f]
// one wave per node; f = lane; csr loads are wave-uniform broadcasts.
__global__ void k_conv(const float* __restrict__ H, const int* __restrict__ row_ptr,
                       const int2* __restrict__ csr, const float* __restrict__ dis,
                       const float* __restrict__ bias, float* __restrict__ OUT,
                       int n, int do_relu) {
    int g = blockIdx.x * blockDim.x + threadIdx.x;
    int node = g >> 6;
    int f = g & 63;
    if (node >= n) return;
    int beg = row_ptr[node];
    int end = row_ptr[node + 1];
    float acc = 0.f;
    #pragma unroll 4
    for (int j = beg; j < end; ++j) {
        int2 e = csr[j];
        acc = fmaf(__int_as_float(e.y), H[(size_t)e.x * FEAT + f], acc);
    }
    float di = dis[node];
    acc = fmaf(di * di, H[(size_t)node * FEAT + f], acc);
    acc += bias[f];
    if (do_relu) acc = fmaxf(acc, 0.f);
    OUT[(size_t)node * FEAT + f] = acc;
}

// ---------------- pooling + head ----------------

// Segmented sum over sorted batch: one wave per POOL_SPAN nodes, lane = feature.
// Atomic flush only when graph id changes within the span (+1 final flush).
__global__ void k_pool(const float* __restrict__ H, const int* __restrict__ batch,
                       float* __restrict__ sums, int n) {
    int wid = (blockIdx.x * blockDim.x + threadIdx.x) >> 6;
    int lane = threadIdx.x & 63;
    int beg = wid * POOL_SPAN;
    if (beg >= n) return;
    int end = min(beg + POOL_SPAN, n);
    float acc = 0.f;
    int cur = batch[beg];
    for (int i = beg; i < end; ++i) {
        int g = batch[i];                        // wave-uniform broadcast
        if (g != cur) {                          // wave-uniform branch
            atomicAdd(&sums[cur * FEAT + lane], acc);
            acc = 0.f;
            cur = g;
        }
        acc += H[(size_t)i * FEAT + lane];       // coalesced 256B/wave
    }
    atomicAdd(&sums[cur * FEAT + lane], acc);
}

__device__ __forceinline__ int lb(const int* __restrict__ a, int n, int v) {
    int lo = 0, hi = n;
    while (lo < hi) { int m = (lo + hi) >> 1; if (a[m] < v) lo = m + 1; else hi = m; }
    return lo;
}

// mean + linear head fused: out[g][c] = bl[c] + (sums[g]/cnt_g) . Wl[:,c]
__global__ void k_head(const float* __restrict__ sums, const int* __restrict__ batch,
                       int n, const float* __restrict__ Wl, const float* __restrict__ bl,
                       float* __restrict__ out, int C) {
    int t = threadIdx.x;
    if (t >= NGRAPH * C) return;
    int g = t / C, c = t % C;
    int start = lb(batch, n, g);
    int end = lb(batch, n, g + 1);
    float inv = 1.0f / fmaxf((float)(end - start), 1.0f);
    float acc = bl[c];
    #pragma unroll
    for (int f = 0; f < FEAT; ++f)
        acc = fmaf(sums[g * FEAT + f] * inv, Wl[f * C + c], acc);
    out[g * C + c] = acc;
}

// ---------------- launch ----------------

extern "C" void kernel_launch(void* const* d_in, const int* in_sizes, int n_in,
                              void* d_out, int out_size, void* d_ws, size_t ws_size,
                              hipStream_t stream) {
    const float* x     = (const float*)d_in[0];
    const int*   ei    = (const int*)d_in[1];
    const float* ew    = (const float*)d_in[2];
    const int*   batch = (const int*)d_in[3];
    const float* W1 = (const float*)d_in[4];
    const float* b1 = (const float*)d_in[5];
    const float* W2 = (const float*)d_in[6];
    const float* b2 = (const float*)d_in[7];
    const float* W3 = (const float*)d_in[8];
    const float* b3 = (const float*)d_in[9];
    const float* Wl = (const float*)d_in[10];
    const float* bl = (const float*)d_in[11];
    float* out = (float*)d_out;

    const int N = in_sizes[3];          // batch has N elements
    const int E = in_sizes[2];          // edge_attr has E elements
    const int C = in_sizes[11];         // bl has C elements

    const int* src = ei;
    const int* dst = ei + E;

    // workspace carve-up (256B-aligned); dry-run to verify ws_size first
    size_t need = 0;
    auto sz = [&](size_t bytes) { need += (bytes + 255) & ~(size_t)255; };
    sz((size_t)N * 4); sz((size_t)N * 4); sz((size_t)N * 4);
    sz((size_t)(N + 1) * 4); sz((size_t)N * 4); sz((size_t)SCAN_BLK * 4);
    sz((size_t)E * 8);
    sz((size_t)N * FEAT * 4); sz((size_t)N * FEAT * 4);
    sz((size_t)NGRAPH * FEAT * 4);
    if (need > ws_size) return;   // fail readable (zero output), not fatal

    char* p = (char*)d_ws;
    auto carve = [&](size_t bytes) {
        char* r = p;
        p += (bytes + 255) & ~(size_t)255;
        return r;
    };
    float* deg      = (float*)carve((size_t)N * 4);
    float* dis      = (float*)carve((size_t)N * 4);
    int*   cnt      = (int*)  carve((size_t)N * 4);
    int*   row_ptr  = (int*)  carve((size_t)(N + 1) * 4);
    int*   cursor   = (int*)  carve((size_t)N * 4);
    int*   part     = (int*)  carve((size_t)SCAN_BLK * 4);
    int2*  csr      = (int2*) carve((size_t)E * 8);
    float* bufA     = (float*)carve((size_t)N * FEAT * 4);
    float* bufB     = (float*)carve((size_t)N * FEAT * 4);
    float* sums     = (float*)carve((size_t)NGRAPH * FEAT * 4);

    const int blkN  = (N + 255) / 256;
    const int blkE  = (E + 255) / 256;
    const int nScan = (N + SCAN_BLK - 1) / SCAN_BLK;
    const int blkNF = (N * FEAT + 255) / 256;
    const int blkG  = (N + 63) / 64;
    const int blkP  = (N + 4 * POOL_SPAN - 1) / (4 * POOL_SPAN);  // 4 waves/block

    // structure preprocessing (layer-invariant)
    k_init<<<blkN, 256, 0, stream>>>(deg, cnt, cursor, sums, N);
    k_deg<<<blkE, 256, 0, stream>>>(dst, ew, deg, cnt, E);
    k_scan_block<<<nScan, SCAN_BLK, 0, stream>>>(cnt, N, row_ptr, part, deg, dis);
    k_scan_top<<<1, SCAN_BLK, 0, stream>>>(part, nScan);
    k_scan_add<<<blkN, 256, 0, stream>>>(row_ptr, part, N, E);
    k_fill<<<blkE, 256, 0, stream>>>(src, dst, ew, dis, row_ptr, cursor, csr, E);

    // layer 1
    k_gemm<<<blkG, 256, 0, stream>>>(x, W1, bufA, N);
    k_conv<<<blkNF, 256, 0, stream>>>(bufA, row_ptr, csr, dis, b1, bufB, N, 1);
    // layer 2
    k_gemm<<<blkG, 256, 0, stream>>>(bufB, W2, bufA, N);
    k_conv<<<blkNF, 256, 0, stream>>>(bufA, row_ptr, csr, dis, b2, bufB, N, 1);
    // layer 3
    k_gemm<<<blkG, 256, 0, stream>>>(bufB, W3, bufA, N);
    k_conv<<<blkNF, 256, 0, stream>>>(bufA, row_ptr, csr, dis, b3, bufB, N, 0);

    // pool + head
    k_pool<<<blkP, 256, 0, stream>>>(bufB, batch, sums, N);
    k_head<<<1, 64, 0, stream>>>(sums, batch, N, Wl, bl, out, C);
}

// Round 10
// 430.767 us; speedup vs baseline: 1.5326x; 1.0870x over previous
//
#include <hip/hip_runtime.h>

// GCN: 3x GCNConv(64->64) + mean-pool(32 graphs) + linear(64->2), fp32.
// Preproc: int-only histogram -> scan -> CSR{src,ew}; deg/dis and norm
// computed FROM the CSR (no float atomics). Conv: float4 lanes, 4 nodes
// per wave (4 independent edge streams -> 4x memory-level parallelism).

#define FEAT 64
#define NGRAPH 32
#define SCAN_BLK 512
#define POOL_SPAN 64

// ---------------- preprocessing ----------------

__global__ void k_init(int* __restrict__ cnt, int* __restrict__ cursor,
                       float* __restrict__ sums, int n) {
    int i = blockIdx.x * blockDim.x + threadIdx.x;
    int stride = gridDim.x * blockDim.x;
    for (; i < n; i += stride) {
        cnt[i] = 0; cursor[i] = 0;
        if (i < NGRAPH * FEAT) sums[i] = 0.0f;
    }
}

// int-only histogram: 1 atomic per edge (was 2 incl. a float atomic)
__global__ void k_cnt(const int* __restrict__ dst, int* __restrict__ cnt, int e) {
    int i = blockIdx.x * blockDim.x + threadIdx.x;
    int stride = gridDim.x * blockDim.x;
    for (; i < e; i += stride) atomicAdd(&cnt[dst[i]], 1);
}

// per-block inclusive scan of cnt -> local-exclusive row_ptr + block sums
__global__ void k_scan_block(const int* __restrict__ cnt, int n,
                             int* __restrict__ row_ptr, int* __restrict__ part) {
    __shared__ int s[SCAN_BLK];
    int tid = threadIdx.x;
    int i = blockIdx.x * SCAN_BLK + tid;
    int v = (i < n) ? cnt[i] : 0;
    s[tid] = v;
    __syncthreads();
    for (int o = 1; o < SCAN_BLK; o <<= 1) {
        int t = (tid >= o) ? s[tid - o] : 0;
        __syncthreads();
        s[tid] += t;
        __syncthreads();
    }
    if (i < n) row_ptr[i] = s[tid] - v;          // local exclusive
    if (tid == SCAN_BLK - 1) part[blockIdx.x] = s[tid];
}

__global__ void k_scan_top(int* __restrict__ part, int nb) {
    __shared__ int s[SCAN_BLK];
    int tid = threadIdx.x;
    int v = (tid < nb) ? part[tid] : 0;
    s[tid] = v;
    __syncthreads();
    for (int o = 1; o < SCAN_BLK; o <<= 1) {
        int t = (tid >= o) ? s[tid - o] : 0;
        __syncthreads();
        s[tid] += t;
        __syncthreads();
    }
    if (tid < nb) part[tid] = s[tid] - v;        // exclusive block offsets
}

__global__ void k_scan_add(int* __restrict__ row_ptr, const int* __restrict__ part,
                           int n, int e) {
    int i = blockIdx.x * blockDim.x + threadIdx.x;
    if (i < n) row_ptr[i] += part[i >> 9];       // 512 = 2^9
    if (i == 0) row_ptr[n] = e;
}

// CSR entry int2{src, ew-bits}; cursor atomic (1 int atomic per edge)
__global__ void k_fill(const int* __restrict__ src, const int* __restrict__ dst,
                       const float* __restrict__ ew,
                       const int* __restrict__ row_ptr, int* __restrict__ cursor,
                       int2* __restrict__ csr, int e) {
    int i = blockIdx.x * blockDim.x + threadIdx.x;
    int stride = gridDim.x * blockDim.x;
    for (; i < e; i += stride) {
        int d = dst[i];
        int pos = row_ptr[d] + atomicAdd(&cursor[d], 1);
        csr[pos] = make_int2(src[i], __float_as_int(ew[i]));
    }
}

// deg = 1 + sum(ew over own CSR row); dis = rsqrt(deg). Thread per node,
// sequential ~128B row read, no atomics.
__global__ void k_degdis(const int* __restrict__ row_ptr, const int2* __restrict__ csr,
                         float* __restrict__ dis, int n) {
    int i = blockIdx.x * blockDim.x + threadIdx.x;
    if (i >= n) return;
    int beg = row_ptr[i], end = row_ptr[i + 1];
    float deg = 1.0f;
    for (int j = beg; j < end; ++j) deg += __int_as_float(csr[j].y);
    dis[i] = rsqrtf(deg);
}

// rewrite csr.y: ew -> dis[src]*ew*dis[dst] (in place, each entry touched once)
__global__ void k_norm(const int* __restrict__ row_ptr, int2* __restrict__ csr,
                       const float* __restrict__ dis, int n) {
    int i = blockIdx.x * blockDim.x + threadIdx.x;
    if (i >= n) return;
    int beg = row_ptr[i], end = row_ptr[i + 1];
    float dd = dis[i];
    for (int j = beg; j < end; ++j) {
        int2 e = csr[j];
        float nm = dis[e.x] * __int_as_float(e.y) * dd;
        csr[j] = make_int2(e.x, __float_as_int(nm));
    }
}

// ---------------- per-layer kernels ----------------

// H[n][64] = X[n][64] @ W[64][64]; W staged in LDS; 64 rows per block.
__global__ void k_gemm(const float* __restrict__ X, const float* __restrict__ W,
                       float* __restrict__ H, int n) {
    __shared__ float w[FEAT * FEAT];
    for (int t = threadIdx.x; t < FEAT * FEAT; t += blockDim.x) w[t] = W[t];
    __syncthreads();
    int j = threadIdx.x & 63;
    int sub = threadIdx.x >> 6;
    int base = blockIdx.x * 64;
    for (int r = sub; r < 64; r += 4) {
        int i = base + r;
        if (i >= n) break;
        const float* xr = X + (size_t)i * FEAT;
        float acc = 0.f;
        #pragma unroll
        for (int k = 0; k < FEAT; ++k) acc = fmaf(xr[k], w[k * FEAT + j], acc);
        H[(size_t)i * FEAT + j] = acc;
    }
}

// float4 lanes: 16 lanes per node (4 features each), 4 nodes per wave ->
// 4 independent edge streams per wave for latency hiding.
__global__ void k_conv(const float4* __restrict__ H4, const int* __restrict__ row_ptr,
                       const int2* __restrict__ csr, const float* __restrict__ dis,
                       const float4* __restrict__ bias4, float4* __restrict__ OUT4,
                       int n, int do_relu) {
    int t = blockIdx.x * blockDim.x + threadIdx.x;
    int node = t >> 4;
    int sub = t & 15;
    if (node >= n) return;
    int beg = row_ptr[node];
    int end = row_ptr[node + 1];
    float4 acc = make_float4(0.f, 0.f, 0.f, 0.f);
    #pragma unroll 4
    for (int j = beg; j < end; ++j) {
        int2 e = csr[j];                       // quarter-wave uniform
        float nm = __int_as_float(e.y);
        float4 h = H4[e.x * 16 + sub];         // 16 lanes x 16B = 256B/edge
        acc.x = fmaf(nm, h.x, acc.x);
        acc.y = fmaf(nm, h.y, acc.y);
        acc.z = fmaf(nm, h.z, acc.z);
        acc.w = fmaf(nm, h.w, acc.w);
    }
    float di = dis[node];
    float d2 = di * di;
    float4 hs = H4[node * 16 + sub];
    float4 b = bias4[sub];
    acc.x = fmaf(d2, hs.x, acc.x) + b.x;
    acc.y = fmaf(d2, hs.y, acc.y) + b.y;
    acc.z = fmaf(d2, hs.z, acc.z) + b.z;
    acc.w = fmaf(d2, hs.w, acc.w) + b.w;
    if (do_relu) {
        acc.x = fmaxf(acc.x, 0.f); acc.y = fmaxf(acc.y, 0.f);
        acc.z = fmaxf(acc.z, 0.f); acc.w = fmaxf(acc.w, 0.f);
    }
    OUT4[node * 16 + sub] = acc;
}

// ---------------- pooling + head ----------------

// Segmented sum over sorted batch: one wave per POOL_SPAN nodes, lane = feature.
__global__ void k_pool(const float* __restrict__ H, const int* __restrict__ batch,
                       float* __restrict__ sums, int n) {
    int wid = (blockIdx.x * blockDim.x + threadIdx.x) >> 6;
    int lane = threadIdx.x & 63;
    int beg = wid * POOL_SPAN;
    if (beg >= n) return;
    int end = min(beg + POOL_SPAN, n);
    float acc = 0.f;
    int cur = batch[beg];
    for (int i = beg; i < end; ++i) {
        int g = batch[i];                        // wave-uniform broadcast
        if (g != cur) {                          // wave-uniform branch
            atomicAdd(&sums[cur * FEAT + lane], acc);
            acc = 0.f;
            cur = g;
        }
        acc += H[(size_t)i * FEAT + lane];       // coalesced 256B/wave
    }
    atomicAdd(&sums[cur * FEAT + lane], acc);
}

__device__ __forceinline__ int lb(const int* __restrict__ a, int n, int v) {
    int lo = 0, hi = n;
    while (lo < hi) { int m = (lo + hi) >> 1; if (a[m] < v) lo = m + 1; else hi = m; }
    return lo;
}

// mean + linear head fused: out[g][c] = bl[c] + (sums[g]/cnt_g) . Wl[:,c]
__global__ void k_head(const float* __restrict__ sums, const int* __restrict__ batch,
                       int n, const float* __restrict__ Wl, const float* __restrict__ bl,
                       float* __restrict__ out, int C) {
    int t = threadIdx.x;
    if (t >= NGRAPH * C) return;
    int g = t / C, c = t % C;
    int start = lb(batch, n, g);
    int end = lb(batch, n, g + 1);
    float inv = 1.0f / fmaxf((float)(end - start), 1.0f);
    float acc = bl[c];
    #pragma unroll
    for (int f = 0; f < FEAT; ++f)
        acc = fmaf(sums[g * FEAT + f] * inv, Wl[f * C + c], acc);
    out[g * C + c] = acc;
}

// ---------------- launch ----------------

extern "C" void kernel_launch(void* const* d_in, const int* in_sizes, int n_in,
                              void* d_out, int out_size, void* d_ws, size_t ws_size,
                              hipStream_t stream) {
    const float* x     = (const float*)d_in[0];
    const int*   ei    = (const int*)d_in[1];
    const float* ew    = (const float*)d_in[2];
    const int*   batch = (const int*)d_in[3];
    const float* W1 = (const float*)d_in[4];
    const float* b1 = (const float*)d_in[5];
    const float* W2 = (const float*)d_in[6];
    const float* b2 = (const float*)d_in[7];
    const float* W3 = (const float*)d_in[8];
    const float* b3 = (const float*)d_in[9];
    const float* Wl = (const float*)d_in[10];
    const float* bl = (const float*)d_in[11];
    float* out = (float*)d_out;

    const int N = in_sizes[3];          // batch has N elements
    const int E = in_sizes[2];          // edge_attr has E elements
    const int C = in_sizes[11];         // bl has C elements

    const int* src = ei;
    const int* dst = ei + E;

    // workspace carve-up (256B-aligned); dry-run to verify ws_size first
    size_t need = 0;
    auto sz = [&](size_t bytes) { need += (bytes + 255) & ~(size_t)255; };
    sz((size_t)N * 4); sz((size_t)N * 4); sz((size_t)(N + 1) * 4);
    sz((size_t)N * 4); sz((size_t)SCAN_BLK * 4);
    sz((size_t)E * 8);
    sz((size_t)N * FEAT * 4); sz((size_t)N * FEAT * 4);
    sz((size_t)NGRAPH * FEAT * 4);
    if (need > ws_size) return;   // fail readable (zero output), not fatal

    char* p = (char*)d_ws;
    auto carve = [&](size_t bytes) {
        char* r = p;
        p += (bytes + 255) & ~(size_t)255;
        return r;
    };
    float* dis      = (float*)carve((size_t)N * 4);
    int*   cnt      = (int*)  carve((size_t)N * 4);
    int*   row_ptr  = (int*)  carve((size_t)(N + 1) * 4);
    int*   cursor   = (int*)  carve((size_t)N * 4);
    int*   part     = (int*)  carve((size_t)SCAN_BLK * 4);
    int2*  csr      = (int2*) carve((size_t)E * 8);
    float* bufA     = (float*)carve((size_t)N * FEAT * 4);
    float* bufB     = (float*)carve((size_t)N * FEAT * 4);
    float* sums     = (float*)carve((size_t)NGRAPH * FEAT * 4);

    const int blkN  = (N + 255) / 256;
    const int blkE  = (E + 255) / 256;
    const int nScan = (N + SCAN_BLK - 1) / SCAN_BLK;
    const int blkC  = (N * 16 + 255) / 256;      // conv: 16 lanes/node
    const int blkG  = (N + 63) / 64;
    const int blkP  = (N + 4 * POOL_SPAN - 1) / (4 * POOL_SPAN);  // 4 waves/block

    // structure preprocessing (layer-invariant)
    k_init<<<blkN, 256, 0, stream>>>(cnt, cursor, sums, N);
    k_cnt<<<blkE, 256, 0, stream>>>(dst, cnt, E);
    k_scan_block<<<nScan, SCAN_BLK, 0, stream>>>(cnt, N, row_ptr, part);
    k_scan_top<<<1, SCAN_BLK, 0, stream>>>(part, nScan);
    k_scan_add<<<blkN, 256, 0, stream>>>(row_ptr, part, N, E);
    k_fill<<<blkE, 256, 0, stream>>>(src, dst, ew, row_ptr, cursor, csr, E);
    k_degdis<<<blkN, 256, 0, stream>>>(row_ptr, csr, dis, N);
    k_norm<<<blkN, 256, 0, stream>>>(row_ptr, csr, dis, N);

    // layer 1
    k_gemm<<<blkG, 256, 0, stream>>>(x, W1, bufA, N);
    k_conv<<<blkC, 256, 0, stream>>>((const float4*)bufA, row_ptr, csr, dis,
                                     (const float4*)b1, (float4*)bufB, N, 1);
    // layer 2
    k_gemm<<<blkG, 256, 0, stream>>>(bufB, W2, bufA, N);
    k_conv<<<blkC, 256, 0, stream>>>((const float4*)bufA, row_ptr, csr, dis,
                                     (const float4*)b2, (float4*)bufB, N, 1);
    // layer 3
    k_gemm<<<blkG, 256, 0, stream>>>(bufB, W3, bufA, N);
    k_conv<<<blkC, 256, 0, stream>>>((const float4*)bufA, row_ptr, csr, dis,
                                     (const float4*)b3, (float4*)bufB, N, 0);

    // pool + head
    k_pool<<<blkP, 256, 0, stream>>>(bufB, batch, sums, N);
    k_head<<<1, 64, 0, stream>>>(sums, batch, N, Wl, bl, out, C);
}

// Round 12
// 394.884 us; speedup vs baseline: 1.6718x; 1.0909x over previous
//
#include <hip/hip_runtime.h>

// GCN: 3x GCNConv(64->64) + mean-pool(32 graphs) + linear(64->2), fp32.
// Preproc: histogram WITH RANK CAPTURE (atomic old-value) -> scan -> CSR fill
// with no atomics. deg/dis/norm from CSR (no float atomics anywhere).
// Conv: float4 lanes, 4 nodes/wave (4 independent edge streams).

#define FEAT 64
#define NGRAPH 32
#define SCAN_BLK 512
#define POOL_SPAN 64

// ---------------- preprocessing ----------------

// histogram + rank: rank[i] = old count = position of edge i within its dst row
__global__ void k_cnt(const int* __restrict__ dst, int* __restrict__ cnt,
                      int* __restrict__ rank, int e) {
    int i = blockIdx.x * blockDim.x + threadIdx.x;
    int stride = gridDim.x * blockDim.x;
    for (; i < e; i += stride) rank[i] = atomicAdd(&cnt[dst[i]], 1);
}

// per-block inclusive scan of cnt -> local-exclusive row_ptr + block sums
__global__ void k_scan_block(const int* __restrict__ cnt, int n,
                             int* __restrict__ row_ptr, int* __restrict__ part) {
    __shared__ int s[SCAN_BLK];
    int tid = threadIdx.x;
    int i = blockIdx.x * SCAN_BLK + tid;
    int v = (i < n) ? cnt[i] : 0;
    s[tid] = v;
    __syncthreads();
    for (int o = 1; o < SCAN_BLK; o <<= 1) {
        int t = (tid >= o) ? s[tid - o] : 0;
        __syncthreads();
        s[tid] += t;
        __syncthreads();
    }
    if (i < n) row_ptr[i] = s[tid] - v;          // local exclusive
    if (tid == SCAN_BLK - 1) part[blockIdx.x] = s[tid];
}

__global__ void k_scan_top(int* __restrict__ part, int nb) {
    __shared__ int s[SCAN_BLK];
    int tid = threadIdx.x;
    int v = (tid < nb) ? part[tid] : 0;
    s[tid] = v;
    __syncthreads();
    for (int o = 1; o < SCAN_BLK; o <<= 1) {
        int t = (tid >= o) ? s[tid - o] : 0;
        __syncthreads();
        s[tid] += t;
        __syncthreads();
    }
    if (tid < nb) part[tid] = s[tid] - v;        // exclusive block offsets
}

__global__ void k_scan_add(int* __restrict__ row_ptr, const int* __restrict__ part,
                           int n, int e) {
    int i = blockIdx.x * blockDim.x + threadIdx.x;
    if (i < n) row_ptr[i] += part[i >> 9];       // 512 = 2^9
    if (i == 0) row_ptr[n] = e;
}

// CSR entry int2{src, ew-bits}; pos from precomputed rank -> NO atomics
__global__ void k_fill(const int* __restrict__ src, const int* __restrict__ dst,
                       const float* __restrict__ ew, const int* __restrict__ rank,
                       const int* __restrict__ row_ptr, int2* __restrict__ csr, int e) {
    int i = blockIdx.x * blockDim.x + threadIdx.x;
    int stride = gridDim.x * blockDim.x;
    for (; i < e; i += stride) {
        int pos = row_ptr[dst[i]] + rank[i];
        csr[pos] = make_int2(src[i], __float_as_int(ew[i]));
    }
}

// deg = 1 + sum(ew over own CSR row); dis = rsqrt(deg). No atomics.
__global__ void k_degdis(const int* __restrict__ row_ptr, const int2* __restrict__ csr,
                         float* __restrict__ dis, int n) {
    int i = blockIdx.x * blockDim.x + threadIdx.x;
    if (i >= n) return;
    int beg = row_ptr[i], end = row_ptr[i + 1];
    float deg = 1.0f;
    for (int j = beg; j < end; ++j) deg += __int_as_float(csr[j].y);
    dis[i] = rsqrtf(deg);
}

// rewrite csr.y: ew -> dis[src]*ew*dis[dst] (in place, each entry touched once)
__global__ void k_norm(const int* __restrict__ row_ptr, int2* __restrict__ csr,
                       const float* __restrict__ dis, int n) {
    int i = blockIdx.x * blockDim.x + threadIdx.x;
    if (i >= n) return;
    int beg = row_ptr[i], end = row_ptr[i + 1];
    float dd = dis[i];
    for (int j = beg; j < end; ++j) {
        int2 e = csr[j];
        float nm = dis[e.x] * __int_as_float(e.y) * dd;
        csr[j] = make_int2(e.x, __float_as_int(nm));
    }
}

// ---------------- per-layer kernels ----------------

// H[n][64] = X[n][64] @ W[64][64]; W staged in LDS; 64 rows per block.
__global__ void k_gemm(const float* __restrict__ X, const float* __restrict__ W,
                       float* __restrict__ H, int n) {
    __shared__ float w[FEAT * FEAT];
    for (int t = threadIdx.x; t < FEAT * FEAT; t += blockDim.x) w[t] = W[t];
    __syncthreads();
    int j = threadIdx.x & 63;
    int sub = threadIdx.x >> 6;
    int base = blockIdx.x * 64;
    for (int r = sub; r < 64; r += 4) {
        int i = base + r;
        if (i >= n) break;
        const float* xr = X + (size_t)i * FEAT;
        float acc = 0.f;
        #pragma unroll
        for (int k = 0; k < FEAT; ++k) acc = fmaf(xr[k], w[k * FEAT + j], acc);
        H[(size_t)i * FEAT + j] = acc;
    }
}

// float4 lanes: 16 lanes per node (4 features each), 4 nodes per wave ->
// 4 independent edge streams per wave for latency hiding.
__global__ void k_conv(const float4* __restrict__ H4, const int* __restrict__ row_ptr,
                       const int2* __restrict__ csr, const float* __restrict__ dis,
                       const float4* __restrict__ bias4, float4* __restrict__ OUT4,
                       int n, int do_relu) {
    int t = blockIdx.x * blockDim.x + threadIdx.x;
    int node = t >> 4;
    int sub = t & 15;
    if (node >= n) return;
    int beg = row_ptr[node];
    int end = row_ptr[node + 1];
    float4 acc = make_float4(0.f, 0.f, 0.f, 0.f);
    #pragma unroll 4
    for (int j = beg; j < end; ++j) {
        int2 e = csr[j];                       // quarter-wave uniform
        float nm = __int_as_float(e.y);
        float4 h = H4[e.x * 16 + sub];         // 16 lanes x 16B = 256B/edge
        acc.x = fmaf(nm, h.x, acc.x);
        acc.y = fmaf(nm, h.y, acc.y);
        acc.z = fmaf(nm, h.z, acc.z);
        acc.w = fmaf(nm, h.w, acc.w);
    }
    float di = dis[node];
    float d2 = di * di;
    float4 hs = H4[node * 16 + sub];
    float4 b = bias4[sub];
    acc.x = fmaf(d2, hs.x, acc.x) + b.x;
    acc.y = fmaf(d2, hs.y, acc.y) + b.y;
    acc.z = fmaf(d2, hs.z, acc.z) + b.z;
    acc.w = fmaf(d2, hs.w, acc.w) + b.w;
    if (do_relu) {
        acc.x = fmaxf(acc.x, 0.f); acc.y = fmaxf(acc.y, 0.f);
        acc.z = fmaxf(acc.z, 0.f); acc.w = fmaxf(acc.w, 0.f);
    }
    OUT4[node * 16 + sub] = acc;
}

// ---------------- pooling + head ----------------

// Segmented sum over sorted batch: one wave per POOL_SPAN nodes, lane = feature.
__global__ void k_pool(const float* __restrict__ H, const int* __restrict__ batch,
                       float* __restrict__ sums, int n) {
    int wid = (blockIdx.x * blockDim.x + threadIdx.x) >> 6;
    int lane = threadIdx.x & 63;
    int beg = wid * POOL_SPAN;
    if (beg >= n) return;
    int end = min(beg + POOL_SPAN, n);
    float acc = 0.f;
    int cur = batch[beg];
    for (int i = beg; i < end; ++i) {
        int g = batch[i];                        // wave-uniform broadcast
        if (g != cur) {                          // wave-uniform branch
            atomicAdd(&sums[cur * FEAT + lane], acc);
            acc = 0.f;
            cur = g;
        }
        acc += H[(size_t)i * FEAT + lane];       // coalesced 256B/wave
    }
    atomicAdd(&sums[cur * FEAT + lane], acc);
}

__device__ __forceinline__ int lb(const int* __restrict__ a, int n, int v) {
    int lo = 0, hi = n;
    while (lo < hi) { int m = (lo + hi) >> 1; if (a[m] < v) lo = m + 1; else hi = m; }
    return lo;
}

// mean + linear head fused: out[g][c] = bl[c] + (sums[g]/cnt_g) . Wl[:,c]
__global__ void k_head(const float* __restrict__ sums, const int* __restrict__ batch,
                       int n, const float* __restrict__ Wl, const float* __restrict__ bl,
                       float* __restrict__ out, int C) {
    int t = threadIdx.x;
    if (t >= NGRAPH * C) return;
    int g = t / C, c = t % C;
    int start = lb(batch, n, g);
    int end = lb(batch, n, g + 1);
    float inv = 1.0f / fmaxf((float)(end - start), 1.0f);
    float acc = bl[c];
    #pragma unroll
    for (int f = 0; f < FEAT; ++f)
        acc = fmaf(sums[g * FEAT + f] * inv, Wl[f * C + c], acc);
    out[g * C + c] = acc;
}

// ---------------- launch ----------------

extern "C" void kernel_launch(void* const* d_in, const int* in_sizes, int n_in,
                              void* d_out, int out_size, void* d_ws, size_t ws_size,
                              hipStream_t stream) {
    const float* x     = (const float*)d_in[0];
    const int*   ei    = (const int*)d_in[1];
    const float* ew    = (const float*)d_in[2];
    const int*   batch = (const int*)d_in[3];
    const float* W1 = (const float*)d_in[4];
    const float* b1 = (const float*)d_in[5];
    const float* W2 = (const float*)d_in[6];
    const float* b2 = (const float*)d_in[7];
    const float* W3 = (const float*)d_in[8];
    const float* b3 = (const float*)d_in[9];
    const float* Wl = (const float*)d_in[10];
    const float* bl = (const float*)d_in[11];
    float* out = (float*)d_out;

    const int N = in_sizes[3];          // batch has N elements
    const int E = in_sizes[2];          // edge_attr has E elements
    const int C = in_sizes[11];         // bl has C elements

    const int* src = ei;
    const int* dst = ei + E;

    // workspace carve-up (256B-aligned); dry-run to verify ws_size first
    size_t need = 0;
    auto sz = [&](size_t bytes) { need += (bytes + 255) & ~(size_t)255; };
    sz((size_t)N * 4); sz((size_t)N * 4); sz((size_t)(N + 1) * 4);
    sz((size_t)E * 4); sz((size_t)SCAN_BLK * 4);
    sz((size_t)E * 8);
    sz((size_t)N * FEAT * 4); sz((size_t)N * FEAT * 4);
    sz((size_t)NGRAPH * FEAT * 4);
    if (need > ws_size) return;   // fail readable (zero output), not fatal

    char* p = (char*)d_ws;
    auto carve = [&](size_t bytes) {
        char* r = p;
        p += (bytes + 255) & ~(size_t)255;
        return r;
    };
    float* dis      = (float*)carve((size_t)N * 4);
    int*   cnt      = (int*)  carve((size_t)N * 4);
    int*   row_ptr  = (int*)  carve((size_t)(N + 1) * 4);
    int*   rank     = (int*)  carve((size_t)E * 4);
    int*   part     = (int*)  carve((size_t)SCAN_BLK * 4);
    int2*  csr      = (int2*) carve((size_t)E * 8);
    float* bufA     = (float*)carve((size_t)N * FEAT * 4);
    float* bufB     = (float*)carve((size_t)N * FEAT * 4);
    float* sums     = (float*)carve((size_t)NGRAPH * FEAT * 4);

    const int blkN  = (N + 255) / 256;
    const int blkE  = (E + 255) / 256;
    const int nScan = (N + SCAN_BLK - 1) / SCAN_BLK;
    const int blkC  = (N * 16 + 255) / 256;      // conv: 16 lanes/node
    const int blkG  = (N + 63) / 64;
    const int blkP  = (N + 4 * POOL_SPAN - 1) / (4 * POOL_SPAN);  // 4 waves/block

    // zero cnt + sums (capture-safe async memsets; harness uses these itself)
    hipMemsetAsync(cnt, 0, (size_t)N * 4, stream);
    hipMemsetAsync(sums, 0, (size_t)NGRAPH * FEAT * 4, stream);

    // structure preprocessing (layer-invariant)
    k_cnt<<<blkE, 256, 0, stream>>>(dst, cnt, rank, E);
    k_scan_block<<<nScan, SCAN_BLK, 0, stream>>>(cnt, N, row_ptr, part);
    k_scan_top<<<1, SCAN_BLK, 0, stream>>>(part, nScan);
    k_scan_add<<<blkN, 256, 0, stream>>>(row_ptr, part, N, E);
    k_fill<<<blkE, 256, 0, stream>>>(src, dst, ew, rank, row_ptr, csr, E);
    k_degdis<<<blkN, 256, 0, stream>>>(row_ptr, csr, dis, N);
    k_norm<<<blkN, 256, 0, stream>>>(row_ptr, csr, dis, N);

    // layer 1
    k_gemm<<<blkG, 256, 0, stream>>>(x, W1, bufA, N);
    k_conv<<<blkC, 256, 0, stream>>>((const float4*)bufA, row_ptr, csr, dis,
                                     (const float4*)b1, (float4*)bufB, N, 1);
    // layer 2
    k_gemm<<<blkG, 256, 0, stream>>>(bufB, W2, bufA, N);
    k_conv<<<blkC, 256, 0, stream>>>((const float4*)bufA, row_ptr, csr, dis,
                                     (const float4*)b2, (float4*)bufB, N, 1);
    // layer 3
    k_gemm<<<blkG, 256, 0, stream>>>(bufB, W3, bufA, N);
    k_conv<<<blkC, 256, 0, stream>>>((const float4*)bufA, row_ptr, csr, dis,
                                     (const float4*)b3, (float4*)bufB, N, 0);

    // pool + head
    k_pool<<<blkP, 256, 0, stream>>>(bufB, batch, sums, N);
    k_head<<<1, 64, 0, stream>>>(sums, batch, N, Wl, bl, out, C);
}

// Round 13
// 320.664 us; speedup vs baseline: 2.0588x; 1.2315x over previous
//
#include <hip/hip_runtime.h>

// GCN: 3x GCNConv(64->64) + mean-pool(32 graphs) + linear(64->2), fp32.
// Preproc: histogram WITH RANK CAPTURE -> scan -> CSR fill (no atomics).
// GEMM: 16 threads/row x float4 cols, dual accumulators (8 FMA chains),
// 3125 blocks. Conv: float4 lanes, 4 nodes/wave.

#define FEAT 64
#define NGRAPH 32
#define SCAN_BLK 512
#define POOL_SPAN 64

// ---------------- preprocessing ----------------

// histogram + rank: rank[i] = old count = position of edge i within its dst row
__global__ void k_cnt(const int* __restrict__ dst, int* __restrict__ cnt,
                      int* __restrict__ rank, int e) {
    int i = blockIdx.x * blockDim.x + threadIdx.x;
    int stride = gridDim.x * blockDim.x;
    for (; i < e; i += stride) rank[i] = atomicAdd(&cnt[dst[i]], 1);
}

// per-block inclusive scan of cnt -> local-exclusive row_ptr + block sums
__global__ void k_scan_block(const int* __restrict__ cnt, int n,
                             int* __restrict__ row_ptr, int* __restrict__ part) {
    __shared__ int s[SCAN_BLK];
    int tid = threadIdx.x;
    int i = blockIdx.x * SCAN_BLK + tid;
    int v = (i < n) ? cnt[i] : 0;
    s[tid] = v;
    __syncthreads();
    for (int o = 1; o < SCAN_BLK; o <<= 1) {
        int t = (tid >= o) ? s[tid - o] : 0;
        __syncthreads();
        s[tid] += t;
        __syncthreads();
    }
    if (i < n) row_ptr[i] = s[tid] - v;          // local exclusive
    if (tid == SCAN_BLK - 1) part[blockIdx.x] = s[tid];
}

__global__ void k_scan_top(int* __restrict__ part, int nb) {
    __shared__ int s[SCAN_BLK];
    int tid = threadIdx.x;
    int v = (tid < nb) ? part[tid] : 0;
    s[tid] = v;
    __syncthreads();
    for (int o = 1; o < SCAN_BLK; o <<= 1) {
        int t = (tid >= o) ? s[tid - o] : 0;
        __syncthreads();
        s[tid] += t;
        __syncthreads();
    }
    if (tid < nb) part[tid] = s[tid] - v;        // exclusive block offsets
}

__global__ void k_scan_add(int* __restrict__ row_ptr, const int* __restrict__ part,
                           int n, int e) {
    int i = blockIdx.x * blockDim.x + threadIdx.x;
    if (i < n) row_ptr[i] += part[i >> 9];       // 512 = 2^9
    if (i == 0) row_ptr[n] = e;
}

// CSR entry int2{src, ew-bits}; pos from precomputed rank -> NO atomics
__global__ void k_fill(const int* __restrict__ src, const int* __restrict__ dst,
                       const float* __restrict__ ew, const int* __restrict__ rank,
                       const int* __restrict__ row_ptr, int2* __restrict__ csr, int e) {
    int i = blockIdx.x * blockDim.x + threadIdx.x;
    int stride = gridDim.x * blockDim.x;
    for (; i < e; i += stride) {
        int pos = row_ptr[dst[i]] + rank[i];
        csr[pos] = make_int2(src[i], __float_as_int(ew[i]));
    }
}

// deg = 1 + sum(ew over own CSR row); dis = rsqrt(deg). No atomics.
__global__ void k_degdis(const int* __restrict__ row_ptr, const int2* __restrict__ csr,
                         float* __restrict__ dis, int n) {
    int i = blockIdx.x * blockDim.x + threadIdx.x;
    if (i >= n) return;
    int beg = row_ptr[i], end = row_ptr[i + 1];
    float deg = 1.0f;
    for (int j = beg; j < end; ++j) deg += __int_as_float(csr[j].y);
    dis[i] = rsqrtf(deg);
}

// rewrite csr.y: ew -> dis[src]*ew*dis[dst] (in place, each entry touched once)
__global__ void k_norm(const int* __restrict__ row_ptr, int2* __restrict__ csr,
                       const float* __restrict__ dis, int n) {
    int i = blockIdx.x * blockDim.x + threadIdx.x;
    if (i >= n) return;
    int beg = row_ptr[i], end = row_ptr[i + 1];
    float dd = dis[i];
    for (int j = beg; j < end; ++j) {
        int2 e = csr[j];
        float nm = dis[e.x] * __int_as_float(e.y) * dd;
        csr[j] = make_int2(e.x, __float_as_int(nm));
    }
}

// ---------------- per-layer kernels ----------------

// H = X @ W. 16 threads per row (each owns 4 output cols as float4),
// 16 rows per 256-thread block -> N/16 blocks. Dual float4 accumulators
// give 8 independent FMA chains of depth 32 (was 1 chain of 64).
__global__ void k_gemm(const float4* __restrict__ X4, const float* __restrict__ W,
                       float4* __restrict__ H4, int n) {
    __shared__ float4 w4[FEAT][16];              // w4[k][j4] = W[k][4j4..4j4+3]
    int tid = threadIdx.x;
    for (int t = tid; t < FEAT * 16; t += 256) {
        int k = t >> 4, j4 = t & 15;
        w4[k][j4] = ((const float4*)W)[k * 16 + j4];
    }
    __syncthreads();
    int j4 = tid & 15;                           // col group
    int r  = tid >> 4;                           // row within block
    int i  = blockIdx.x * 16 + r;
    if (i >= n) return;
    const float4* xr = X4 + (size_t)i * 16;
    float4 a0 = make_float4(0.f, 0.f, 0.f, 0.f);
    float4 a1 = make_float4(0.f, 0.f, 0.f, 0.f);
    #pragma unroll
    for (int kk = 0; kk < 16; ++kk) {
        float4 xv = xr[kk];                      // 16B broadcast within row group
        int k = kk * 4;
        float4 w0 = w4[k + 0][j4];
        float4 w1 = w4[k + 1][j4];
        float4 w2 = w4[k + 2][j4];
        float4 w3 = w4[k + 3][j4];
        a0.x = fmaf(xv.x, w0.x, a0.x); a0.y = fmaf(xv.x, w0.y, a0.y);
        a0.z = fmaf(xv.x, w0.z, a0.z); a0.w = fmaf(xv.x, w0.w, a0.w);
        a1.x = fmaf(xv.y, w1.x, a1.x); a1.y = fmaf(xv.y, w1.y, a1.y);
        a1.z = fmaf(xv.y, w1.z, a1.z); a1.w = fmaf(xv.y, w1.w, a1.w);
        a0.x = fmaf(xv.z, w2.x, a0.x); a0.y = fmaf(xv.z, w2.y, a0.y);
        a0.z = fmaf(xv.z, w2.z, a0.z); a0.w = fmaf(xv.z, w2.w, a0.w);
        a1.x = fmaf(xv.w, w3.x, a1.x); a1.y = fmaf(xv.w, w3.y, a1.y);
        a1.z = fmaf(xv.w, w3.z, a1.z); a1.w = fmaf(xv.w, w3.w, a1.w);
    }
    float4 r4;
    r4.x = a0.x + a1.x; r4.y = a0.y + a1.y;
    r4.z = a0.z + a1.z; r4.w = a0.w + a1.w;
    H4[(size_t)i * 16 + j4] = r4;                // 256B coalesced per row group
}

// float4 lanes: 16 lanes per node (4 features each), 4 nodes per wave ->
// 4 independent edge streams per wave for latency hiding.
__global__ void k_conv(const float4* __restrict__ H4, const int* __restrict__ row_ptr,
                       const int2* __restrict__ csr, const float* __restrict__ dis,
                       const float4* __restrict__ bias4, float4* __restrict__ OUT4,
                       int n, int do_relu) {
    int t = blockIdx.x * blockDim.x + threadIdx.x;
    int node = t >> 4;
    int sub = t & 15;
    if (node >= n) return;
    int beg = row_ptr[node];
    int end = row_ptr[node + 1];
    float4 acc = make_float4(0.f, 0.f, 0.f, 0.f);
    #pragma unroll 4
    for (int j = beg; j < end; ++j) {
        int2 e = csr[j];                       // quarter-wave uniform
        float nm = __int_as_float(e.y);
        float4 h = H4[e.x * 16 + sub];         // 16 lanes x 16B = 256B/edge
        acc.x = fmaf(nm, h.x, acc.x);
        acc.y = fmaf(nm, h.y, acc.y);
        acc.z = fmaf(nm, h.z, acc.z);
        acc.w = fmaf(nm, h.w, acc.w);
    }
    float di = dis[node];
    float d2 = di * di;
    float4 hs = H4[node * 16 + sub];
    float4 b = bias4[sub];
    acc.x = fmaf(d2, hs.x, acc.x) + b.x;
    acc.y = fmaf(d2, hs.y, acc.y) + b.y;
    acc.z = fmaf(d2, hs.z, acc.z) + b.z;
    acc.w = fmaf(d2, hs.w, acc.w) + b.w;
    if (do_relu) {
        acc.x = fmaxf(acc.x, 0.f); acc.y = fmaxf(acc.y, 0.f);
        acc.z = fmaxf(acc.z, 0.f); acc.w = fmaxf(acc.w, 0.f);
    }
    OUT4[node * 16 + sub] = acc;
}

// ---------------- pooling + head ----------------

// Segmented sum over sorted batch: one wave per POOL_SPAN nodes, lane = feature.
__global__ void k_pool(const float* __restrict__ H, const int* __restrict__ batch,
                       float* __restrict__ sums, int n) {
    int wid = (blockIdx.x * blockDim.x + threadIdx.x) >> 6;
    int lane = threadIdx.x & 63;
    int beg = wid * POOL_SPAN;
    if (beg >= n) return;
    int end = min(beg + POOL_SPAN, n);
    float acc = 0.f;
    int cur = batch[beg];
    for (int i = beg; i < end; ++i) {
        int g = batch[i];                        // wave-uniform broadcast
        if (g != cur) {                          // wave-uniform branch
            atomicAdd(&sums[cur * FEAT + lane], acc);
            acc = 0.f;
            cur = g;
        }
        acc += H[(size_t)i * FEAT + lane];       // coalesced 256B/wave
    }
    atomicAdd(&sums[cur * FEAT + lane], acc);
}

__device__ __forceinline__ int lb(const int* __restrict__ a, int n, int v) {
    int lo = 0, hi = n;
    while (lo < hi) { int m = (lo + hi) >> 1; if (a[m] < v) lo = m + 1; else hi = m; }
    return lo;
}

// mean + linear head fused: out[g][c] = bl[c] + (sums[g]/cnt_g) . Wl[:,c]
__global__ void k_head(const float* __restrict__ sums, const int* __restrict__ batch,
                       int n, const float* __restrict__ Wl, const float* __restrict__ bl,
                       float* __restrict__ out, int C) {
    int t = threadIdx.x;
    if (t >= NGRAPH * C) return;
    int g = t / C, c = t % C;
    int start = lb(batch, n, g);
    int end = lb(batch, n, g + 1);
    float inv = 1.0f / fmaxf((float)(end - start), 1.0f);
    float acc = bl[c];
    #pragma unroll
    for (int f = 0; f < FEAT; ++f)
        acc = fmaf(sums[g * FEAT + f] * inv, Wl[f * C + c], acc);
    out[g * C + c] = acc;
}

// ---------------- launch ----------------

extern "C" void kernel_launch(void* const* d_in, const int* in_sizes, int n_in,
                              void* d_out, int out_size, void* d_ws, size_t ws_size,
                              hipStream_t stream) {
    const float* x     = (const float*)d_in[0];
    const int*   ei    = (const int*)d_in[1];
    const float* ew    = (const float*)d_in[2];
    const int*   batch = (const int*)d_in[3];
    const float* W1 = (const float*)d_in[4];
    const float* b1 = (const float*)d_in[5];
    const float* W2 = (const float*)d_in[6];
    const float* b2 = (const float*)d_in[7];
    const float* W3 = (const float*)d_in[8];
    const float* b3 = (const float*)d_in[9];
    const float* Wl = (const float*)d_in[10];
    const float* bl = (const float*)d_in[11];
    float* out = (float*)d_out;

    const int N = in_sizes[3];          // batch has N elements
    const int E = in_sizes[2];          // edge_attr has E elements
    const int C = in_sizes[11];         // bl has C elements

    const int* src = ei;
    const int* dst = ei + E;

    // workspace carve-up (256B-aligned); dry-run to verify ws_size first
    size_t need = 0;
    auto sz = [&](size_t bytes) { need += (bytes + 255) & ~(size_t)255; };
    sz((size_t)N * 4); sz((size_t)N * 4); sz((size_t)(N + 1) * 4);
    sz((size_t)E * 4); sz((size_t)SCAN_BLK * 4);
    sz((size_t)E * 8);
    sz((size_t)N * FEAT * 4); sz((size_t)N * FEAT * 4);
    sz((size_t)NGRAPH * FEAT * 4);
    if (need > ws_size) return;   // fail readable (zero output), not fatal

    char* p = (char*)d_ws;
    auto carve = [&](size_t bytes) {
        char* r = p;
        p += (bytes + 255) & ~(size_t)255;
        return r;
    };
    float* dis      = (float*)carve((size_t)N * 4);
    int*   cnt      = (int*)  carve((size_t)N * 4);
    int*   row_ptr  = (int*)  carve((size_t)(N + 1) * 4);
    int*   rank     = (int*)  carve((size_t)E * 4);
    int*   part     = (int*)  carve((size_t)SCAN_BLK * 4);
    int2*  csr      = (int2*) carve((size_t)E * 8);
    float* bufA     = (float*)carve((size_t)N * FEAT * 4);
    float* bufB     = (float*)carve((size_t)N * FEAT * 4);
    float* sums     = (float*)carve((size_t)NGRAPH * FEAT * 4);

    const int blkN  = (N + 255) / 256;
    const int blkE  = (E + 255) / 256;
    const int nScan = (N + SCAN_BLK - 1) / SCAN_BLK;
    const int blkC  = (N * 16 + 255) / 256;      // conv: 16 lanes/node
    const int blkG  = (N + 15) / 16;             // gemm: 16 rows/block
    const int blkP  = (N + 4 * POOL_SPAN - 1) / (4 * POOL_SPAN);  // 4 waves/block

    // zero cnt + sums (capture-safe async memsets; harness uses these itself)
    hipMemsetAsync(cnt, 0, (size_t)N * 4, stream);
    hipMemsetAsync(sums, 0, (size_t)NGRAPH * FEAT * 4, stream);

    // structure preprocessing (layer-invariant)
    k_cnt<<<blkE, 256, 0, stream>>>(dst, cnt, rank, E);
    k_scan_block<<<nScan, SCAN_BLK, 0, stream>>>(cnt, N, row_ptr, part);
    k_scan_top<<<1, SCAN_BLK, 0, stream>>>(part, nScan);
    k_scan_add<<<blkN, 256, 0, stream>>>(row_ptr, part, N, E);
    k_fill<<<blkE, 256, 0, stream>>>(src, dst, ew, rank, row_ptr, csr, E);
    k_degdis<<<blkN, 256, 0, stream>>>(row_ptr, csr, dis, N);
    k_norm<<<blkN, 256, 0, stream>>>(row_ptr, csr, dis, N);

    // layer 1
    k_gemm<<<blkG, 256, 0, stream>>>((const float4*)x, W1, (float4*)bufA, N);
    k_conv<<<blkC, 256, 0, stream>>>((const float4*)bufA, row_ptr, csr, dis,
                                     (const float4*)b1, (float4*)bufB, N, 1);
    // layer 2
    k_gemm<<<blkG, 256, 0, stream>>>((const float4*)bufB, W2, (float4*)bufA, N);
    k_conv<<<blkC, 256, 0, stream>>>((const float4*)bufA, row_ptr, csr, dis,
                                     (const float4*)b2, (float4*)bufB, N, 1);
    // layer 3
    k_gemm<<<blkG, 256, 0, stream>>>((const float4*)bufB, W3, (float4*)bufA, N);
    k_conv<<<blkC, 256, 0, stream>>>((const float4*)bufA, row_ptr, csr, dis,
                                     (const float4*)b3, (float4*)bufB, N, 0);

    // pool + head
    k_pool<<<blkP, 256, 0, stream>>>(bufB, batch, sums, N);
    k_head<<<1, 64, 0, stream>>>(sums, batch, N, Wl, bl, out, C);
}